// Round 8
// baseline (279.057 us; speedup 1.0000x reference)
//
#include <hip/hip_runtime.h>

typedef __bf16 bf16;
typedef bf16 v8bf __attribute__((ext_vector_type(8)));
typedef bf16 v4bf __attribute__((ext_vector_type(4)));
typedef float v4f __attribute__((ext_vector_type(4)));
typedef float v16f __attribute__((ext_vector_type(16)));
typedef unsigned int u32;
typedef u32 v4u __attribute__((ext_vector_type(4)));

#define GAS __attribute__((address_space(1)))
#define LAS __attribute__((address_space(3)))

constexpr int D    = 1024;   // d_model
constexpr int ROWS = 8192;   // B*S

// ---------------------------------------------------------------- cast ----
__global__ __launch_bounds__(256) void cast_all(
    const float* __restrict__ x,
    const float* __restrict__ wq, const float* __restrict__ wk,
    const float* __restrict__ wv, const float* __restrict__ wo,
    bf16* __restrict__ xb, bf16* __restrict__ wqb, bf16* __restrict__ wkb,
    bf16* __restrict__ wvb, bf16* __restrict__ wob)
{
    int i = blockIdx.x * 256 + threadIdx.x;
    const float* src; bf16* dst; int off;
    if (i < 2 * 1024 * 1024) { src = x; dst = xb; off = i; }
    else {
        int j = i - 2 * 1024 * 1024;
        int w = j >> 18;
        off = j & ((1 << 18) - 1);
        src = (w == 0) ? wq : (w == 1) ? wk : (w == 2) ? wv : wo;
        dst = (w == 0) ? wqb : (w == 1) ? wkb : (w == 2) ? wvb : wob;
    }
    float4 v = ((const float4*)src)[off];
    v4bf o;
    o[0] = (bf16)v.x; o[1] = (bf16)v.y; o[2] = (bf16)v.z; o[3] = (bf16)v.w;
    ((v4bf*)dst)[off] = o;
}

// ---------------------------------------------------------------- GEMM ----
// Deep-pipelined C = A (ROWS x D) * W^T.  BM=256, BN=128, BK=64.
// 512 threads = 8 waves (4M x 2N), 64x64 output per wave, 16x16x32 MFMA.
// Triple-buffered LDS (144 KiB) filled by global_load_lds (width 16) with
// pre-swizzled SOURCE addresses (16B-chunk ^= row&7): swizzled reads are
// conflict-free (measured 0).
// K-loop: per K-tile, TWO phases (one per k-half). Each phase:
//   8 ds_read_b128 ; 3 global_load_lds (tile t+2) ; [vmcnt(6) once/tile]
//   s_barrier ; lgkmcnt(0) ; setprio(1) 16 MFMA setprio(0) ; s_barrier
// MODE 0: W = [3072][1024] QKV concat; epilogue by col-range: Q scaled
//         bf16, K bf16, V transposed into VtG[b][h][d][s].
// MODE 1: W = wo; fp32 out + bias + residual X.
template<int MODE, int NTN>
__global__ __launch_bounds__(512, 2) void gemm8(
    const bf16* __restrict__ A, const bf16* __restrict__ W,
    bf16* __restrict__ Oq, bf16* __restrict__ Ok, bf16* __restrict__ Ov,
    float* __restrict__ Of, const float* __restrict__ bias,
    const float* __restrict__ X)
{
    __shared__ bf16 Abuf[3][256 * 64];   // 96 KiB
    __shared__ bf16 Bbuf[3][128 * 64];   // 48 KiB

    // XCD-chunked decode: consecutive wgid on one XCD share mTile (A panel).
    const int id   = blockIdx.x;
    const int wgid = (id & 7) * (4 * NTN) + (id >> 3);
    const int mT   = wgid / NTN;
    const int nT   = wgid - mT * NTN;
    const long rowA0 = (long)mT * 256;
    const long colB0 = (long)nT * 128;

    const int tid  = threadIdx.x;
    const int lane = tid & 63;
    const int wave = tid >> 6;
    const int quad = lane >> 4;
    const int l16  = lane & 15;
    const int wm   = (wave >> 1) * 64;   // 4 M-waves
    const int wn   = (wave & 1) * 64;    // 2 N-waves

    // staging source (pre-swizzled column)
    const int srow = wave * 8 + (lane >> 3);
    const int scol = ((lane & 7) ^ (lane >> 3)) * 8;
    const bf16* gA = A + (rowA0 + srow) * D + scol;
    const bf16* gB = W + (colB0 + srow) * D + scol;
    const int dstOff = wave * 512;       // elems; wave-uniform LDS base part

    const v4f vzero = {0.f, 0.f, 0.f, 0.f};
    v4f acc[4][4];
    #pragma unroll
    for (int i = 0; i < 4; i++)
        #pragma unroll
        for (int j = 0; j < 4; j++) acc[i][j] = vzero;

    // swizzled read offsets (elems): row*64 + ((ks*4+quad)^(l16&7))*8
    int sa[2], sb[2];
    #pragma unroll
    for (int ks = 0; ks < 2; ks++) {
        const int ch = ((ks * 4 + quad) ^ (l16 & 7)) * 8;
        sa[ks] = (wm + l16) * 64 + ch;
        sb[ks] = (wn + l16) * 64 + ch;
    }

    auto stage_full = [&](int bi, int t) {
        const bf16* a = gA + (long)t * 64;
        const bf16* b = gB + (long)t * 64;
        #pragma unroll
        for (int i = 0; i < 4; i++)
            __builtin_amdgcn_global_load_lds(
                (const GAS void*)(a + (long)i * 64 * D),
                (LAS void*)(&Abuf[bi][i * 4096 + dstOff]), 16, 0, 0);
        #pragma unroll
        for (int i = 0; i < 2; i++)
            __builtin_amdgcn_global_load_lds(
                (const GAS void*)(b + (long)i * 64 * D),
                (LAS void*)(&Bbuf[bi][i * 4096 + dstOff]), 16, 0, 0);
    };

    constexpr int NT = 16;   // K=1024 / BK=64
    stage_full(0, 0);
    stage_full(1, 1);
    asm volatile("s_waitcnt vmcnt(6)" ::: "memory");
    __builtin_amdgcn_s_barrier();

    for (int t = 0; t < NT; ++t) {
        const int bi = t % 3;
        const int bs = (t + 2) % 3;
        const bf16* As = &Abuf[bi][0];
        const bf16* Bs = &Bbuf[bi][0];
        #pragma unroll
        for (int ks = 0; ks < 2; ++ks) {
            // this phase's fragments (8 x ds_read_b128)
            v8bf af[4], bf4[4];
            #pragma unroll
            for (int mi = 0; mi < 4; mi++)
                af[mi] = *(const v8bf*)(As + sa[ks] + mi * 1024);
            #pragma unroll
            for (int ni = 0; ni < 4; ni++)
                bf4[ni] = *(const v8bf*)(Bs + sb[ks] + ni * 1024);

            // stage half of tile t+2 (3 x global_load_lds)
            if (t + 2 < NT) {
                const bf16* a2 = gA + (long)(t + 2) * 64;
                const bf16* b2 = gB + (long)(t + 2) * 64;
                if (ks == 0) {
                    __builtin_amdgcn_global_load_lds(
                        (const GAS void*)(a2),
                        (LAS void*)(&Abuf[bs][dstOff]), 16, 0, 0);
                    __builtin_amdgcn_global_load_lds(
                        (const GAS void*)(a2 + (long)64 * D),
                        (LAS void*)(&Abuf[bs][4096 + dstOff]), 16, 0, 0);
                    __builtin_amdgcn_global_load_lds(
                        (const GAS void*)(b2),
                        (LAS void*)(&Bbuf[bs][dstOff]), 16, 0, 0);
                } else {
                    __builtin_amdgcn_global_load_lds(
                        (const GAS void*)(a2 + (long)128 * D),
                        (LAS void*)(&Abuf[bs][2 * 4096 + dstOff]), 16, 0, 0);
                    __builtin_amdgcn_global_load_lds(
                        (const GAS void*)(a2 + (long)192 * D),
                        (LAS void*)(&Abuf[bs][3 * 4096 + dstOff]), 16, 0, 0);
                    __builtin_amdgcn_global_load_lds(
                        (const GAS void*)(b2 + (long)64 * D),
                        (LAS void*)(&Bbuf[bs][4096 + dstOff]), 16, 0, 0);
                }
            }

            // once per tile: make buf[t+1] ready before crossing into it
            if (ks == 1 && t + 1 < NT) {
                if (t + 2 < NT) asm volatile("s_waitcnt vmcnt(6)" ::: "memory");
                else            asm volatile("s_waitcnt vmcnt(0)" ::: "memory");
            }

            __builtin_amdgcn_s_barrier();
            asm volatile("s_waitcnt lgkmcnt(0)" ::: "memory");
            __builtin_amdgcn_sched_barrier(0);
            __builtin_amdgcn_s_setprio(1);
            #pragma unroll
            for (int mi = 0; mi < 4; mi++)
                #pragma unroll
                for (int ni = 0; ni < 4; ni++)
                    acc[mi][ni] = __builtin_amdgcn_mfma_f32_16x16x32_bf16(
                        af[mi], bf4[ni], acc[mi][ni], 0, 0, 0);
            __builtin_amdgcn_s_setprio(0);
            __builtin_amdgcn_s_barrier();
        }
    }

    const float qscale = 0.125f * 1.44269504f;

    if (MODE == 0) {
        const int z = (int)(colB0 >> 10);
        #pragma unroll
        for (int mi = 0; mi < 4; mi++) {
            #pragma unroll
            for (int ni = 0; ni < 4; ni++) {
                const long col = colB0 + wn + ni * 16 + l16;
                const long c   = col & 1023;
                const long row0 = rowA0 + wm + mi * 16 + quad * 4;
                if (z == 2) {
                    const long h_ = c >> 6, dd = c & 63;
                    const long b_ = row0 >> 11, s0 = row0 & 2047;
                    v4bf pk;
                    #pragma unroll
                    for (int r = 0; r < 4; r++) pk[r] = (bf16)acc[mi][ni][r];
                    *(v4bf*)(Ov + ((b_ * 16 + h_) * 64 + dd) * 2048 + s0) = pk;
                } else {
                    bf16* Ob = (z == 0) ? Oq : Ok;
                    #pragma unroll
                    for (int r = 0; r < 4; r++) {
                        float v = acc[mi][ni][r];
                        if (z == 0) v *= qscale;
                        Ob[(row0 + r) * D + c] = (bf16)v;
                    }
                }
            }
        }
    } else {
        #pragma unroll
        for (int mi = 0; mi < 4; mi++) {
            #pragma unroll
            for (int ni = 0; ni < 4; ni++) {
                const long col = colB0 + wn + ni * 16 + l16;
                const float bv = bias[col];
                #pragma unroll
                for (int r = 0; r < 4; r++) {
                    const long row = rowA0 + wm + mi * 16 + quad * 4 + r;
                    Of[row * D + col] = acc[mi][ni][r] + bv + X[row * D + col];
                }
            }
        }
    }
}

// ----------------------------------------------------------- attention ----
// 256 blocks (4 q-tiles x 64 (h,b) groups, XCD-grouped), 512 threads =
// 8 waves x 64 q-rows (q-tile 512). Per wave: TWO 32-row C-tiles share
// every K/V LDS read (halves LDS-pipe traffic, the r6 bottleneck).
// l accumulated on the MFMA pipe via a ones-B MFMA (o_l += P*1), exactly
// consistent with the bf16 P used in PV; kills the VALU adds and the
// entire epilogue shuffle tree. 6-deep K/V ring (96 KiB) staged 4-5
// tiles ahead by global_load_lds; ONE barrier per 2 k-tiles with counted
// vmcnt(4) (never 0 mid-loop). Dual-tile pair body gives within-wave ILP
// (QK of tile t+1 overlaps exp of tile t).
__global__ __launch_bounds__(512, 2) void attn_kernel(
    const bf16* __restrict__ Q, const bf16* __restrict__ Kg,
    const bf16* __restrict__ VtG, bf16* __restrict__ O)
{
    const int id  = blockIdx.x;
    const int xcd = id & 7, j = id >> 3;   // j 0..31
    const int qt  = j & 3;
    const int g   = xcd + 8 * (j >> 2);    // 0..63
    const int h   = g & 15, b = g >> 4;

    const int tid  = threadIdx.x;
    const int lane = tid & 63;
    const int wave = tid >> 6;
    const int l31  = lane & 31;
    const int hi   = lane >> 5;

    __shared__ bf16 Kt[6][64 * 64];   // 48 KiB, swizzled
    __shared__ bf16 Vt[6][64 * 64];   // 48 KiB, swizzled

    // Q B-fragments: 2 q-halves x 4 d-frags, resident whole kernel.
    v8bf qB[2][4];
    #pragma unroll
    for (int qh = 0; qh < 2; qh++) {
        const long qrow = (long)(b * 2048 + qt * 512 + wave * 64 + qh * 32 + l31);
        #pragma unroll
        for (int f = 0; f < 4; f++)
            qB[qh][f] = *(const v8bf*)(Q + qrow * D + h * 64 + f * 16 + hi * 8);
    }

    const v16f z16 = {0.f,0.f,0.f,0.f,0.f,0.f,0.f,0.f,
                      0.f,0.f,0.f,0.f,0.f,0.f,0.f,0.f};
    v16f o_acc[2][2], o_l[2];
    #pragma unroll
    for (int qh = 0; qh < 2; qh++) {
        o_acc[qh][0] = z16; o_acc[qh][1] = z16; o_l[qh] = z16;
    }

    const bf16 one = (bf16)1.0f;
    v8bf ones;
    #pragma unroll
    for (int i = 0; i < 8; i++) ones[i] = one;

    // staging: row iR (0..63), 16B chunk c8; source column pre-swizzled so
    // the wave-linear DMA fill produces LDS[row][chunk c^(row&7)] layout.
    const int iR  = tid >> 3;
    const int c8  = tid & 7;
    const int csw = ((c8 ^ (iR & 7)) * 8);
    const bf16* kSrc = Kg  + (long)b * 2048 * D + h * 64 + csw + (long)iR * D;
    const bf16* vSrc = VtG + (long)(b * 16 + h) * 64 * 2048 + csw + (long)iR * 2048;
    const int ldsOff = wave * 512;   // elems; wave-uniform base, lane*16B fill

    auto stage = [&](int slot, int t) {
        __builtin_amdgcn_global_load_lds(
            (const GAS void*)(kSrc + (long)t * 64 * D),
            (LAS void*)(&Kt[slot][ldsOff]), 16, 0, 0);
        __builtin_amdgcn_global_load_lds(
            (const GAS void*)(vSrc + t * 64),
            (LAS void*)(&Vt[slot][ldsOff]), 16, 0, 0);
    };

    auto compute = [&](const bf16* kb, const bf16* vb) {
        #pragma unroll
        for (int ko = 0; ko < 2; ko++) {
            const int krow = ko * 32 + l31;
            const int ksw  = krow & 7;
            v8bf kA[4];
            #pragma unroll
            for (int f = 0; f < 4; f++)
                kA[f] = *(const v8bf*)(kb + krow * 64 + (((2 * f + hi) ^ ksw) * 8));
            __builtin_amdgcn_s_setprio(1);
            v16f st0 = __builtin_amdgcn_mfma_f32_32x32x16_bf16(kA[0], qB[0][0], z16, 0, 0, 0);
            v16f st1 = __builtin_amdgcn_mfma_f32_32x32x16_bf16(kA[0], qB[1][0], z16, 0, 0, 0);
            #pragma unroll
            for (int f = 1; f < 4; f++) {
                st0 = __builtin_amdgcn_mfma_f32_32x32x16_bf16(kA[f], qB[0][f], st0, 0, 0, 0);
                st1 = __builtin_amdgcn_mfma_f32_32x32x16_bf16(kA[f], qB[1][f], st1, 0, 0, 0);
            }
            __builtin_amdgcn_s_setprio(0);

            float p0[16], p1[16];
            #pragma unroll
            for (int r = 0; r < 16; r++) {
                p0[r] = __builtin_amdgcn_exp2f(st0[r]);
                p1[r] = __builtin_amdgcn_exp2f(st1[r]);
            }

            #pragma unroll
            for (int u = 0; u < 2; u++) {
                const int s = ko * 2 + u;
                u32 a0, a1, b0, b1, c0, c1, d0, d1;
                asm("v_cvt_pk_bf16_f32 %0, %1, %2" : "=v"(a0) : "v"(p0[u*8+0]), "v"(p0[u*8+1]));
                asm("v_cvt_pk_bf16_f32 %0, %1, %2" : "=v"(a1) : "v"(p0[u*8+2]), "v"(p0[u*8+3]));
                asm("v_cvt_pk_bf16_f32 %0, %1, %2" : "=v"(b0) : "v"(p0[u*8+4]), "v"(p0[u*8+5]));
                asm("v_cvt_pk_bf16_f32 %0, %1, %2" : "=v"(b1) : "v"(p0[u*8+6]), "v"(p0[u*8+7]));
                asm("v_permlane32_swap_b32 %0, %1" : "+v"(a0), "+v"(b0));
                asm("v_permlane32_swap_b32 %0, %1" : "+v"(a1), "+v"(b1));
                asm("v_cvt_pk_bf16_f32 %0, %1, %2" : "=v"(c0) : "v"(p1[u*8+0]), "v"(p1[u*8+1]));
                asm("v_cvt_pk_bf16_f32 %0, %1, %2" : "=v"(c1) : "v"(p1[u*8+2]), "v"(p1[u*8+3]));
                asm("v_cvt_pk_bf16_f32 %0, %1, %2" : "=v"(d0) : "v"(p1[u*8+4]), "v"(p1[u*8+5]));
                asm("v_cvt_pk_bf16_f32 %0, %1, %2" : "=v"(d1) : "v"(p1[u*8+6]), "v"(p1[u*8+7]));
                asm("v_permlane32_swap_b32 %0, %1" : "+v"(c0), "+v"(d0));
                asm("v_permlane32_swap_b32 %0, %1" : "+v"(c1), "+v"(d1));
                v4u w0; w0[0] = a0; w0[1] = a1; w0[2] = b0; w0[3] = b1;
                v4u w1; w1[0] = c0; w1[1] = c1; w1[2] = d0; w1[3] = d1;
                const v8bf pa0 = __builtin_bit_cast(v8bf, w0);
                const v8bf pa1 = __builtin_bit_cast(v8bf, w1);
                const int vsw = (l31 & 7);
                v8bf vb0 = *(const v8bf*)(vb + (l31)      * 64 + (((2 * s + hi) ^ vsw) * 8));
                v8bf vb1 = *(const v8bf*)(vb + (32 + l31) * 64 + (((2 * s + hi) ^ vsw) * 8));
                __builtin_amdgcn_s_setprio(1);
                o_acc[0][0] = __builtin_amdgcn_mfma_f32_32x32x16_bf16(pa0, vb0, o_acc[0][0], 0, 0, 0);
                o_acc[0][1] = __builtin_amdgcn_mfma_f32_32x32x16_bf16(pa0, vb1, o_acc[0][1], 0, 0, 0);
                o_acc[1][0] = __builtin_amdgcn_mfma_f32_32x32x16_bf16(pa1, vb0, o_acc[1][0], 0, 0, 0);
                o_acc[1][1] = __builtin_amdgcn_mfma_f32_32x32x16_bf16(pa1, vb1, o_acc[1][1], 0, 0, 0);
                o_l[0] = __builtin_amdgcn_mfma_f32_32x32x16_bf16(pa0, ones, o_l[0], 0, 0, 0);
                o_l[1] = __builtin_amdgcn_mfma_f32_32x32x16_bf16(pa1, ones, o_l[1], 0, 0, 0);
                __builtin_amdgcn_s_setprio(0);
            }
        }
    };

    // prologue: tiles 0..3 into slots 0..3
    stage(0, 0); stage(1, 1); stage(2, 2); stage(3, 3);
    asm volatile("s_waitcnt vmcnt(4)" ::: "memory");
    __builtin_amdgcn_s_barrier();

    int sA = 0;   // compute slot of even tile of this pair (0,2,4 cycle)
    for (int p = 0; p < 16; ++p) {
        const int t4 = 2 * p + 4;
        if (t4 < 32) {
            int ss0 = sA + 4; if (ss0 >= 6) ss0 -= 6;
            int ss1 = sA + 5; if (ss1 >= 6) ss1 -= 6;
            stage(ss0, t4);
            stage(ss1, t4 + 1);
        }
        compute(&Kt[sA][0], &Vt[sA][0]);
        compute(&Kt[sA + 1][0], &Vt[sA + 1][0]);
        if (p < 15) {
            if (p < 14) asm volatile("s_waitcnt vmcnt(4)" ::: "memory");
            else        asm volatile("s_waitcnt vmcnt(0)" ::: "memory");
            __builtin_amdgcn_s_barrier();
        }
        sA += 2; if (sA >= 6) sA -= 6;
    }

    // epilogue: o_l[qh][r] = l for C-row qp(r) (all cols equal) -- no shuffles
    const long obase = (long)(b * 2048 + qt * 512 + wave * 64);
    #pragma unroll
    for (int qh = 0; qh < 2; qh++) {
        #pragma unroll
        for (int r = 0; r < 16; r++) {
            const int qp = (r & 3) + 8 * (r >> 2) + 4 * hi;
            const float inv = 1.f / o_l[qh][r];
            const long row = obase + qh * 32 + qp;
            O[row * D + h * 64 + l31]      = (bf16)(o_acc[qh][0][r] * inv);
            O[row * D + h * 64 + 32 + l31] = (bf16)(o_acc[qh][1][r] * inv);
        }
    }
}

// ------------------------------------------------------------------ LN ----
__global__ __launch_bounds__(256) void ln_kernel(
    const float* __restrict__ g, const float* __restrict__ beta,
    float* __restrict__ out)
{
    const int row = blockIdx.x;
    const int t = threadIdx.x;
    const int lane = t & 63, wave = t >> 6;
    const long base = (long)row * D + t * 4;

    float4 yv = *(const float4*)(out + base);
    float y0 = yv.x, y1 = yv.y, y2 = yv.z, y3 = yv.w;
    float s1 = y0 + y1 + y2 + y3;
    float s2 = y0*y0 + y1*y1 + y2*y2 + y3*y3;
    #pragma unroll
    for (int off = 1; off < 64; off <<= 1) {
        s1 += __shfl_xor(s1, off);
        s2 += __shfl_xor(s2, off);
    }
    __shared__ float r1[4], r2[4];
    if (lane == 0) { r1[wave] = s1; r2[wave] = s2; }
    __syncthreads();
    float S1 = r1[0] + r1[1] + r1[2] + r1[3];
    float S2 = r2[0] + r2[1] + r2[2] + r2[3];
    float mu  = S1 * (1.f / 1024.f);
    float var = S2 * (1.f / 1024.f) - mu * mu;
    float rsd = rsqrtf(var + 1e-5f);

    float4 gv = *(const float4*)(g + t * 4);
    float4 bv = *(const float4*)(beta + t * 4);
    float4 o;
    o.x = (y0 - mu) * rsd * gv.x + bv.x;
    o.y = (y1 - mu) * rsd * gv.y + bv.y;
    o.z = (y2 - mu) * rsd * gv.z + bv.z;
    o.w = (y3 - mu) * rsd * gv.w + bv.w;
    *(float4*)(out + base) = o;
}

// ---------------------------------------------------------------- launch --
extern "C" void kernel_launch(void* const* d_in, const int* in_sizes, int n_in,
                              void* d_out, int out_size, void* d_ws, size_t ws_size,
                              hipStream_t stream)
{
    const float* x   = (const float*)d_in[0];
    const float* wq  = (const float*)d_in[1];
    const float* wk  = (const float*)d_in[2];
    const float* wv  = (const float*)d_in[3];
    const float* wo  = (const float*)d_in[4];
    const float* bo  = (const float*)d_in[5];
    const float* lng = (const float*)d_in[6];
    const float* lnb = (const float*)d_in[7];
    float* out = (float*)d_out;

    char* ws = (char*)d_ws;
    bf16* xb  = (bf16*)(ws);                            // 16 MiB
    bf16* wqb = (bf16*)(ws + (size_t)16 * 1024 * 1024); // 4 x 2 MiB (contig QKV,O)
    bf16* wkb = wqb + 1024 * 1024;
    bf16* wvb = wkb + 1024 * 1024;
    bf16* wob = wvb + 1024 * 1024;
    bf16* Qb  = (bf16*)(ws + (size_t)24 * 1024 * 1024); // 4 x 16 MiB
    bf16* Kb  = Qb + (size_t)ROWS * D;
    bf16* VtG = Kb + (size_t)ROWS * D;                  // V transposed [b][h][d][s]
    bf16* Ab  = VtG + (size_t)ROWS * D;                 // total 88 MiB

    cast_all<<<12288, 256, 0, stream>>>(x, wq, wk, wv, wo,
                                        xb, wqb, wkb, wvb, wob);

    // QKV: one dispatch, W = [3072][1024] (wq|wk|wv contiguous). 768 blocks
    // = exactly 3 rounds of 256 CUs at 1 block/CU.
    gemm8<0, 24><<<768, 512, 0, stream>>>(xb, wqb, Qb, Kb, VtG,
                                          nullptr, nullptr, nullptr);

    attn_kernel<<<dim3(256, 1, 1), 512, 0, stream>>>(Qb, Kb, VtG, Ab);

    // Output proj: 256 blocks = exactly 1 full round.
    gemm8<1, 8><<<256, 512, 0, stream>>>(Ab, wob, nullptr, nullptr, nullptr,
                                         out, bo, x);

    ln_kernel<<<8192, 256, 0, stream>>>(lng, lnb, out);
}

// Round 9
// 278.096 us; speedup vs baseline: 1.0035x; 1.0035x over previous
//
#include <hip/hip_runtime.h>

typedef __bf16 bf16;
typedef bf16 v8bf __attribute__((ext_vector_type(8)));
typedef bf16 v4bf __attribute__((ext_vector_type(4)));
typedef float v4f __attribute__((ext_vector_type(4)));
typedef float v16f __attribute__((ext_vector_type(16)));
typedef unsigned int u32;
typedef u32 v4u __attribute__((ext_vector_type(4)));

#define GAS __attribute__((address_space(1)))
#define LAS __attribute__((address_space(3)))

constexpr int D    = 1024;   // d_model
constexpr int ROWS = 8192;   // B*S

// ---------------------------------------------------------------- cast ----
__global__ __launch_bounds__(256) void cast_all(
    const float* __restrict__ x,
    const float* __restrict__ wq, const float* __restrict__ wk,
    const float* __restrict__ wv, const float* __restrict__ wo,
    bf16* __restrict__ xb, bf16* __restrict__ wqb, bf16* __restrict__ wkb,
    bf16* __restrict__ wvb, bf16* __restrict__ wob)
{
    int i = blockIdx.x * 256 + threadIdx.x;
    const float* src; bf16* dst; int off;
    if (i < 2 * 1024 * 1024) { src = x; dst = xb; off = i; }
    else {
        int j = i - 2 * 1024 * 1024;
        int w = j >> 18;
        off = j & ((1 << 18) - 1);
        src = (w == 0) ? wq : (w == 1) ? wk : (w == 2) ? wv : wo;
        dst = (w == 0) ? wqb : (w == 1) ? wkb : (w == 2) ? wvb : wob;
    }
    float4 v = ((const float4*)src)[off];
    v4bf o;
    o[0] = (bf16)v.x; o[1] = (bf16)v.y; o[2] = (bf16)v.z; o[3] = (bf16)v.w;
    ((v4bf*)dst)[off] = o;
}

// ---------------------------------------------------------------- GEMM ----
// Deep-pipelined C = A (ROWS x D) * W^T.  BM=256, BN=128, BK=32.
// 512 threads = 8 waves (4M x 2N), 64x64 output per wave, 16x16x32 MFMA.
// 3-ring LDS = 72 KiB -> TWO blocks/CU (4 waves/SIMD; r4-r8 ran 1 block/CU
// at 144 KiB and plateaued on TLP). Rows are 64 B (4 x 16B chunks); swizzle
// chunk ^= (row>>1)&3 applied on BOTH the DMA global source column and the
// ds_read address (involution) -> 16 lanes hit 8 distinct 16B slots = 2-way
// = free. Per K-tile: 8 ds_read_b128 ; 3 global_load_lds (tile t+2) ;
// counted vmcnt(3) ; s_barrier ; lgkmcnt(0) ; setprio(1) 16 MFMA
// setprio(0) ; s_barrier.  Never drains vmcnt to 0 mid-loop.
// MODE 0: W = [3072][1024] QKV concat; epilogue by col-range: Q scaled
//         bf16, K bf16, V transposed into VtG[b][h][d][s].
// MODE 1: W = wo; fp32 out + bias + residual X.
template<int MODE, int NTN>
__global__ __launch_bounds__(512, 4) void gemm8(
    const bf16* __restrict__ A, const bf16* __restrict__ W,
    bf16* __restrict__ Oq, bf16* __restrict__ Ok, bf16* __restrict__ Ov,
    float* __restrict__ Of, const float* __restrict__ bias,
    const float* __restrict__ X)
{
    __shared__ bf16 Abuf[3][256 * 32];   // 48 KiB
    __shared__ bf16 Bbuf[3][128 * 32];   // 24 KiB

    // XCD-chunked decode: consecutive wgid on one XCD share mTile (A panel).
    const int id   = blockIdx.x;
    const int wgid = (id & 7) * (4 * NTN) + (id >> 3);
    const int mT   = wgid / NTN;
    const int nT   = wgid - mT * NTN;
    const long rowA0 = (long)mT * 256;
    const long colB0 = (long)nT * 128;

    const int tid  = threadIdx.x;
    const int lane = tid & 63;
    const int wave = tid >> 6;
    const int quad = lane >> 4;
    const int l16  = lane & 15;
    const int wm   = (wave >> 1) * 64;   // 4 M-waves
    const int wn   = (wave & 1) * 64;    // 2 N-waves

    // staging: thread covers A rows rS, rS+128 and B row rS, 16B chunk cS.
    // Source column pre-swizzled: logical chunk at phys p sources p^((r>>1)&3).
    // ((rS+128)>>1)&3 == (rS>>1)&3, so one colS serves both A slots.
    const int rS   = tid >> 2;           // 0..127
    const int cS   = tid & 3;
    const int colS = ((cS ^ ((rS >> 1) & 3)) * 8);
    const bf16* gA = A + (rowA0 + rS) * D + colS;
    const bf16* gB = W + (colB0 + rS) * D + colS;
    const int dstOff = wave * 512;       // elems; wave-uniform LDS base part

    const v4f vzero = {0.f, 0.f, 0.f, 0.f};
    v4f acc[4][4];
    #pragma unroll
    for (int i = 0; i < 4; i++)
        #pragma unroll
        for (int j = 0; j < 4; j++) acc[i][j] = vzero;

    // read offsets (elems): R*32 + ((quad ^ ((R>>1)&3))*8); for R = base+l16
    // with 16-aligned base, (R>>1)&3 == (l16>>1)&3.
    const int rsw = (quad ^ ((l16 >> 1) & 3)) * 8;
    int sa[4], sb[4];
    #pragma unroll
    for (int i = 0; i < 4; i++) {
        sa[i] = (wm + i * 16 + l16) * 32 + rsw;
        sb[i] = (wn + i * 16 + l16) * 32 + rsw;
    }

    auto stage = [&](int bi, int t) {
        const bf16* a = gA + (long)t * 32;
        const bf16* b = gB + (long)t * 32;
        __builtin_amdgcn_global_load_lds(
            (const GAS void*)(a),
            (LAS void*)(&Abuf[bi][dstOff]), 16, 0, 0);
        __builtin_amdgcn_global_load_lds(
            (const GAS void*)(a + (long)128 * D),
            (LAS void*)(&Abuf[bi][4096 + dstOff]), 16, 0, 0);
        __builtin_amdgcn_global_load_lds(
            (const GAS void*)(b),
            (LAS void*)(&Bbuf[bi][dstOff]), 16, 0, 0);
    };

    constexpr int NT = 32;   // K=1024 / BK=32
    stage(0, 0);
    stage(1, 1);
    asm volatile("s_waitcnt vmcnt(3)" ::: "memory");
    __builtin_amdgcn_s_barrier();

    for (int t = 0; t < NT; ++t) {
        const int bi = t % 3;
        const bf16* As = &Abuf[bi][0];
        const bf16* Bs = &Bbuf[bi][0];

        // this tile's fragments (8 x ds_read_b128)
        v8bf af[4], bf4[4];
        #pragma unroll
        for (int mi = 0; mi < 4; mi++)
            af[mi] = *(const v8bf*)(As + sa[mi]);
        #pragma unroll
        for (int ni = 0; ni < 4; ni++)
            bf4[ni] = *(const v8bf*)(Bs + sb[ni]);

        // stage tile t+2 (3 x global_load_lds)
        if (t + 2 < NT) stage((t + 2) % 3, t + 2);

        // make buf[t+1] ready before crossing into it
        if (t + 1 < NT) {
            if (t + 2 < NT) asm volatile("s_waitcnt vmcnt(3)" ::: "memory");
            else            asm volatile("s_waitcnt vmcnt(0)" ::: "memory");
        }

        __builtin_amdgcn_s_barrier();
        asm volatile("s_waitcnt lgkmcnt(0)" ::: "memory");
        __builtin_amdgcn_sched_barrier(0);
        __builtin_amdgcn_s_setprio(1);
        #pragma unroll
        for (int mi = 0; mi < 4; mi++)
            #pragma unroll
            for (int ni = 0; ni < 4; ni++)
                acc[mi][ni] = __builtin_amdgcn_mfma_f32_16x16x32_bf16(
                    af[mi], bf4[ni], acc[mi][ni], 0, 0, 0);
        __builtin_amdgcn_s_setprio(0);
        __builtin_amdgcn_s_barrier();
    }

    const float qscale = 0.125f * 1.44269504f;

    if (MODE == 0) {
        const int z = (int)(colB0 >> 10);
        #pragma unroll
        for (int mi = 0; mi < 4; mi++) {
            #pragma unroll
            for (int ni = 0; ni < 4; ni++) {
                const long col = colB0 + wn + ni * 16 + l16;
                const long c   = col & 1023;
                const long row0 = rowA0 + wm + mi * 16 + quad * 4;
                if (z == 2) {
                    const long h_ = c >> 6, dd = c & 63;
                    const long b_ = row0 >> 11, s0 = row0 & 2047;
                    v4bf pk;
                    #pragma unroll
                    for (int r = 0; r < 4; r++) pk[r] = (bf16)acc[mi][ni][r];
                    *(v4bf*)(Ov + ((b_ * 16 + h_) * 64 + dd) * 2048 + s0) = pk;
                } else {
                    bf16* Ob = (z == 0) ? Oq : Ok;
                    #pragma unroll
                    for (int r = 0; r < 4; r++) {
                        float v = acc[mi][ni][r];
                        if (z == 0) v *= qscale;
                        Ob[(row0 + r) * D + c] = (bf16)v;
                    }
                }
            }
        }
    } else {
        #pragma unroll
        for (int mi = 0; mi < 4; mi++) {
            #pragma unroll
            for (int ni = 0; ni < 4; ni++) {
                const long col = colB0 + wn + ni * 16 + l16;
                const float bv = bias[col];
                #pragma unroll
                for (int r = 0; r < 4; r++) {
                    const long row = rowA0 + wm + mi * 16 + quad * 4 + r;
                    Of[row * D + col] = acc[mi][ni][r] + bv + X[row * D + col];
                }
            }
        }
    }
}

// ----------------------------------------------------------- attention ----
// 256 blocks (4 q-tiles x 64 (h,b) groups, XCD-grouped), 512 threads =
// 8 waves x 64 q-rows (q-tile 512). Per wave: TWO 32-row C-tiles share
// every K/V LDS read. l accumulated on the MFMA pipe via a ones-B MFMA.
// 6-deep K/V ring staged 4-5 tiles ahead; ONE barrier per 2 k-tiles with
// counted vmcnt(4). T15 pair-interleave: per ko, QK of BOTH tiles issues
// before either finish -- tile B's 8 independent MFMAs cover tile A's
// accumulator-read (exp) latency; A's PV issue covers B's exp.
__global__ __launch_bounds__(512, 2) void attn_kernel(
    const bf16* __restrict__ Q, const bf16* __restrict__ Kg,
    const bf16* __restrict__ VtG, bf16* __restrict__ O)
{
    const int id  = blockIdx.x;
    const int xcd = id & 7, j = id >> 3;   // j 0..31
    const int qt  = j & 3;
    const int g   = xcd + 8 * (j >> 2);    // 0..63
    const int h   = g & 15, b = g >> 4;

    const int tid  = threadIdx.x;
    const int lane = tid & 63;
    const int wave = tid >> 6;
    const int l31  = lane & 31;
    const int hi   = lane >> 5;

    __shared__ bf16 Kt[6][64 * 64];   // 48 KiB, swizzled
    __shared__ bf16 Vt[6][64 * 64];   // 48 KiB, swizzled

    // Q B-fragments: 2 q-halves x 4 d-frags, resident whole kernel.
    v8bf qB[2][4];
    #pragma unroll
    for (int qh = 0; qh < 2; qh++) {
        const long qrow = (long)(b * 2048 + qt * 512 + wave * 64 + qh * 32 + l31);
        #pragma unroll
        for (int f = 0; f < 4; f++)
            qB[qh][f] = *(const v8bf*)(Q + qrow * D + h * 64 + f * 16 + hi * 8);
    }

    const v16f z16 = {0.f,0.f,0.f,0.f,0.f,0.f,0.f,0.f,
                      0.f,0.f,0.f,0.f,0.f,0.f,0.f,0.f};
    v16f o_acc[2][2], o_l[2];
    #pragma unroll
    for (int qh = 0; qh < 2; qh++) {
        o_acc[qh][0] = z16; o_acc[qh][1] = z16; o_l[qh] = z16;
    }

    const bf16 one = (bf16)1.0f;
    v8bf ones;
    #pragma unroll
    for (int i = 0; i < 8; i++) ones[i] = one;

    // staging: row iR (0..63), 16B chunk c8; source column pre-swizzled so
    // the wave-linear DMA fill produces LDS[row][chunk c^(row&7)] layout.
    const int iR  = tid >> 3;
    const int c8  = tid & 7;
    const int csw = ((c8 ^ (iR & 7)) * 8);
    const bf16* kSrc = Kg  + (long)b * 2048 * D + h * 64 + csw + (long)iR * D;
    const bf16* vSrc = VtG + (long)(b * 16 + h) * 64 * 2048 + csw + (long)iR * 2048;
    const int ldsOff = wave * 512;   // elems; wave-uniform base, lane*16B fill

    auto stage = [&](int slot, int t) {
        __builtin_amdgcn_global_load_lds(
            (const GAS void*)(kSrc + (long)t * 64 * D),
            (LAS void*)(&Kt[slot][ldsOff]), 16, 0, 0);
        __builtin_amdgcn_global_load_lds(
            (const GAS void*)(vSrc + t * 64),
            (LAS void*)(&Vt[slot][ldsOff]), 16, 0, 0);
    };

    auto qk = [&](const bf16* kb, int ko, v16f& s0, v16f& s1) {
        const int krow = ko * 32 + l31;
        const int ksw  = krow & 7;
        v8bf kA[4];
        #pragma unroll
        for (int f = 0; f < 4; f++)
            kA[f] = *(const v8bf*)(kb + krow * 64 + (((2 * f + hi) ^ ksw) * 8));
        __builtin_amdgcn_s_setprio(1);
        s0 = __builtin_amdgcn_mfma_f32_32x32x16_bf16(kA[0], qB[0][0], z16, 0, 0, 0);
        s1 = __builtin_amdgcn_mfma_f32_32x32x16_bf16(kA[0], qB[1][0], z16, 0, 0, 0);
        #pragma unroll
        for (int f = 1; f < 4; f++) {
            s0 = __builtin_amdgcn_mfma_f32_32x32x16_bf16(kA[f], qB[0][f], s0, 0, 0, 0);
            s1 = __builtin_amdgcn_mfma_f32_32x32x16_bf16(kA[f], qB[1][f], s1, 0, 0, 0);
        }
        __builtin_amdgcn_s_setprio(0);
    };

    auto finish = [&](const bf16* vb, int ko, const v16f& s0, const v16f& s1) {
        float p0[16], p1[16];
        #pragma unroll
        for (int r = 0; r < 16; r++) {
            p0[r] = __builtin_amdgcn_exp2f(s0[r]);
            p1[r] = __builtin_amdgcn_exp2f(s1[r]);
        }
        #pragma unroll
        for (int u = 0; u < 2; u++) {
            const int s = ko * 2 + u;
            u32 a0, a1, b0, b1, c0, c1, d0, d1;
            asm("v_cvt_pk_bf16_f32 %0, %1, %2" : "=v"(a0) : "v"(p0[u*8+0]), "v"(p0[u*8+1]));
            asm("v_cvt_pk_bf16_f32 %0, %1, %2" : "=v"(a1) : "v"(p0[u*8+2]), "v"(p0[u*8+3]));
            asm("v_cvt_pk_bf16_f32 %0, %1, %2" : "=v"(b0) : "v"(p0[u*8+4]), "v"(p0[u*8+5]));
            asm("v_cvt_pk_bf16_f32 %0, %1, %2" : "=v"(b1) : "v"(p0[u*8+6]), "v"(p0[u*8+7]));
            asm("v_permlane32_swap_b32 %0, %1" : "+v"(a0), "+v"(b0));
            asm("v_permlane32_swap_b32 %0, %1" : "+v"(a1), "+v"(b1));
            asm("v_cvt_pk_bf16_f32 %0, %1, %2" : "=v"(c0) : "v"(p1[u*8+0]), "v"(p1[u*8+1]));
            asm("v_cvt_pk_bf16_f32 %0, %1, %2" : "=v"(c1) : "v"(p1[u*8+2]), "v"(p1[u*8+3]));
            asm("v_cvt_pk_bf16_f32 %0, %1, %2" : "=v"(d0) : "v"(p1[u*8+4]), "v"(p1[u*8+5]));
            asm("v_cvt_pk_bf16_f32 %0, %1, %2" : "=v"(d1) : "v"(p1[u*8+6]), "v"(p1[u*8+7]));
            asm("v_permlane32_swap_b32 %0, %1" : "+v"(c0), "+v"(d0));
            asm("v_permlane32_swap_b32 %0, %1" : "+v"(c1), "+v"(d1));
            v4u w0; w0[0] = a0; w0[1] = a1; w0[2] = b0; w0[3] = b1;
            v4u w1; w1[0] = c0; w1[1] = c1; w1[2] = d0; w1[3] = d1;
            const v8bf pa0 = __builtin_bit_cast(v8bf, w0);
            const v8bf pa1 = __builtin_bit_cast(v8bf, w1);
            const int vsw = (l31 & 7);
            v8bf vb0 = *(const v8bf*)(vb + (l31)      * 64 + (((2 * s + hi) ^ vsw) * 8));
            v8bf vb1 = *(const v8bf*)(vb + (32 + l31) * 64 + (((2 * s + hi) ^ vsw) * 8));
            __builtin_amdgcn_s_setprio(1);
            o_acc[0][0] = __builtin_amdgcn_mfma_f32_32x32x16_bf16(pa0, vb0, o_acc[0][0], 0, 0, 0);
            o_acc[0][1] = __builtin_amdgcn_mfma_f32_32x32x16_bf16(pa0, vb1, o_acc[0][1], 0, 0, 0);
            o_acc[1][0] = __builtin_amdgcn_mfma_f32_32x32x16_bf16(pa1, vb0, o_acc[1][0], 0, 0, 0);
            o_acc[1][1] = __builtin_amdgcn_mfma_f32_32x32x16_bf16(pa1, vb1, o_acc[1][1], 0, 0, 0);
            o_l[0] = __builtin_amdgcn_mfma_f32_32x32x16_bf16(pa0, ones, o_l[0], 0, 0, 0);
            o_l[1] = __builtin_amdgcn_mfma_f32_32x32x16_bf16(pa1, ones, o_l[1], 0, 0, 0);
            __builtin_amdgcn_s_setprio(0);
        }
    };

    // prologue: tiles 0..3 into slots 0..3
    stage(0, 0); stage(1, 1); stage(2, 2); stage(3, 3);
    asm volatile("s_waitcnt vmcnt(4)" ::: "memory");
    __builtin_amdgcn_s_barrier();

    int sA = 0;   // compute slot of even tile of this pair (0,2,4 cycle)
    for (int p = 0; p < 16; ++p) {
        const int t4 = 2 * p + 4;
        if (t4 < 32) {
            int ss0 = sA + 4; if (ss0 >= 6) ss0 -= 6;
            int ss1 = sA + 5; if (ss1 >= 6) ss1 -= 6;
            stage(ss0, t4);
            stage(ss1, t4 + 1);
        }
        const bf16* kbA = &Kt[sA][0];
        const bf16* vbA = &Vt[sA][0];
        const bf16* kbB = &Kt[sA + 1][0];
        const bf16* vbB = &Vt[sA + 1][0];
        #pragma unroll
        for (int ko = 0; ko < 2; ko++) {
            v16f sa0, sa1, sb0, sb1;
            qk(kbA, ko, sa0, sa1);
            qk(kbB, ko, sb0, sb1);      // independent MFMAs cover A's latency
            finish(vbA, ko, sa0, sa1);
            finish(vbB, ko, sb0, sb1);
        }
        if (p < 15) {
            if (p < 14) asm volatile("s_waitcnt vmcnt(4)" ::: "memory");
            else        asm volatile("s_waitcnt vmcnt(0)" ::: "memory");
            __builtin_amdgcn_s_barrier();
        }
        sA += 2; if (sA >= 6) sA -= 6;
    }

    // epilogue: o_l[qh][r] = l for C-row qp(r) (all cols equal) -- no shuffles
    const long obase = (long)(b * 2048 + qt * 512 + wave * 64);
    #pragma unroll
    for (int qh = 0; qh < 2; qh++) {
        #pragma unroll
        for (int r = 0; r < 16; r++) {
            const int qp = (r & 3) + 8 * (r >> 2) + 4 * hi;
            const float inv = 1.f / o_l[qh][r];
            const long row = obase + qh * 32 + qp;
            O[row * D + h * 64 + l31]      = (bf16)(o_acc[qh][0][r] * inv);
            O[row * D + h * 64 + 32 + l31] = (bf16)(o_acc[qh][1][r] * inv);
        }
    }
}

// ------------------------------------------------------------------ LN ----
__global__ __launch_bounds__(256) void ln_kernel(
    const float* __restrict__ g, const float* __restrict__ beta,
    float* __restrict__ out)
{
    const int row = blockIdx.x;
    const int t = threadIdx.x;
    const int lane = t & 63, wave = t >> 6;
    const long base = (long)row * D + t * 4;

    float4 yv = *(const float4*)(out + base);
    float y0 = yv.x, y1 = yv.y, y2 = yv.z, y3 = yv.w;
    float s1 = y0 + y1 + y2 + y3;
    float s2 = y0*y0 + y1*y1 + y2*y2 + y3*y3;
    #pragma unroll
    for (int off = 1; off < 64; off <<= 1) {
        s1 += __shfl_xor(s1, off);
        s2 += __shfl_xor(s2, off);
    }
    __shared__ float r1[4], r2[4];
    if (lane == 0) { r1[wave] = s1; r2[wave] = s2; }
    __syncthreads();
    float S1 = r1[0] + r1[1] + r1[2] + r1[3];
    float S2 = r2[0] + r2[1] + r2[2] + r2[3];
    float mu  = S1 * (1.f / 1024.f);
    float var = S2 * (1.f / 1024.f) - mu * mu;
    float rsd = rsqrtf(var + 1e-5f);

    float4 gv = *(const float4*)(g + t * 4);
    float4 bv = *(const float4*)(beta + t * 4);
    float4 o;
    o.x = (y0 - mu) * rsd * gv.x + bv.x;
    o.y = (y1 - mu) * rsd * gv.y + bv.y;
    o.z = (y2 - mu) * rsd * gv.z + bv.z;
    o.w = (y3 - mu) * rsd * gv.w + bv.w;
    *(float4*)(out + base) = o;
}

// ---------------------------------------------------------------- launch --
extern "C" void kernel_launch(void* const* d_in, const int* in_sizes, int n_in,
                              void* d_out, int out_size, void* d_ws, size_t ws_size,
                              hipStream_t stream)
{
    const float* x   = (const float*)d_in[0];
    const float* wq  = (const float*)d_in[1];
    const float* wk  = (const float*)d_in[2];
    const float* wv  = (const float*)d_in[3];
    const float* wo  = (const float*)d_in[4];
    const float* bo  = (const float*)d_in[5];
    const float* lng = (const float*)d_in[6];
    const float* lnb = (const float*)d_in[7];
    float* out = (float*)d_out;

    char* ws = (char*)d_ws;
    bf16* xb  = (bf16*)(ws);                            // 16 MiB
    bf16* wqb = (bf16*)(ws + (size_t)16 * 1024 * 1024); // 4 x 2 MiB (contig QKV,O)
    bf16* wkb = wqb + 1024 * 1024;
    bf16* wvb = wkb + 1024 * 1024;
    bf16* wob = wvb + 1024 * 1024;
    bf16* Qb  = (bf16*)(ws + (size_t)24 * 1024 * 1024); // 4 x 16 MiB
    bf16* Kb  = Qb + (size_t)ROWS * D;
    bf16* VtG = Kb + (size_t)ROWS * D;                  // V transposed [b][h][d][s]
    bf16* Ab  = VtG + (size_t)ROWS * D;                 // total 88 MiB

    cast_all<<<12288, 256, 0, stream>>>(x, wq, wk, wv, wo,
                                        xb, wqb, wkb, wvb, wob);

    // QKV: one dispatch, W = [3072][1024] (wq|wk|wv contiguous).
    gemm8<0, 24><<<768, 512, 0, stream>>>(xb, wqb, Qb, Kb, VtG,
                                          nullptr, nullptr, nullptr);

    attn_kernel<<<dim3(256, 1, 1), 512, 0, stream>>>(Qb, Kb, VtG, Ab);

    // Output proj: 256 blocks, all co-resident at 2 blocks/CU.
    gemm8<1, 8><<<256, 512, 0, stream>>>(Ab, wob, nullptr, nullptr, nullptr,
                                         out, bo, x);

    ln_kernel<<<8192, 256, 0, stream>>>(lng, lnb, out);
}

// Round 10
// 275.210 us; speedup vs baseline: 1.0140x; 1.0105x over previous
//
#include <hip/hip_runtime.h>

typedef __bf16 bf16;
typedef bf16 v8bf __attribute__((ext_vector_type(8)));
typedef bf16 v4bf __attribute__((ext_vector_type(4)));
typedef float v4f __attribute__((ext_vector_type(4)));
typedef float v16f __attribute__((ext_vector_type(16)));
typedef unsigned int u32;
typedef u32 v4u __attribute__((ext_vector_type(4)));

#define GAS __attribute__((address_space(1)))
#define LAS __attribute__((address_space(3)))

constexpr int D    = 1024;   // d_model
constexpr int ROWS = 8192;   // B*S

// ---------------------------------------------------------------- cast ----
__global__ __launch_bounds__(256) void cast_all(
    const float* __restrict__ x,
    const float* __restrict__ wq, const float* __restrict__ wk,
    const float* __restrict__ wv, const float* __restrict__ wo,
    bf16* __restrict__ xb, bf16* __restrict__ wqb, bf16* __restrict__ wkb,
    bf16* __restrict__ wvb, bf16* __restrict__ wob)
{
    int i = blockIdx.x * 256 + threadIdx.x;
    const float* src; bf16* dst; int off;
    if (i < 2 * 1024 * 1024) { src = x; dst = xb; off = i; }
    else {
        int j = i - 2 * 1024 * 1024;
        int w = j >> 18;
        off = j & ((1 << 18) - 1);
        src = (w == 0) ? wq : (w == 1) ? wk : (w == 2) ? wv : wo;
        dst = (w == 0) ? wqb : (w == 1) ? wkb : (w == 2) ? wvb : wob;
    }
    float4 v = ((const float4*)src)[off];
    v4bf o;
    o[0] = (bf16)v.x; o[1] = (bf16)v.y; o[2] = (bf16)v.z; o[3] = (bf16)v.w;
    ((v4bf*)dst)[off] = o;
}

// ---------------------------------------------------------------- GEMM ----
// Deep-pipelined C = A (ROWS x D) * W^T.  BM=256, BN=128, BK=32.
// 512 threads = 8 waves (4M x 2N), 64x64 output per wave, 16x16x32 MFMA.
// 3-ring LDS = 72 KiB -> two blocks/CU. Rows are 64 B (4 x 16B chunks);
// swizzle chunk ^= (row>>1)&3 applied on BOTH the DMA global source column
// and the ds_read address (involution) -> 2-way = free. Per K-tile:
// 8 ds_read_b128 ; 3 global_load_lds (tile t+2) ; counted vmcnt(3) ;
// s_barrier ; lgkmcnt(0) ; setprio(1) 16 MFMA setprio(0) ; s_barrier.
// MODE 0: W = [3072][1024] QKV concat; epilogue by col-range: Q scaled
//         bf16, K bf16, V transposed into VtG[b][h][d][s].
// MODE 1: W = wo; fp32 out + bias + residual X.
template<int MODE, int NTN>
__global__ __launch_bounds__(512, 4) void gemm8(
    const bf16* __restrict__ A, const bf16* __restrict__ W,
    bf16* __restrict__ Oq, bf16* __restrict__ Ok, bf16* __restrict__ Ov,
    float* __restrict__ Of, const float* __restrict__ bias,
    const float* __restrict__ X)
{
    __shared__ bf16 Abuf[3][256 * 32];   // 48 KiB
    __shared__ bf16 Bbuf[3][128 * 32];   // 24 KiB

    // XCD-chunked decode: consecutive wgid on one XCD share mTile (A panel).
    const int id   = blockIdx.x;
    const int wgid = (id & 7) * (4 * NTN) + (id >> 3);
    const int mT   = wgid / NTN;
    const int nT   = wgid - mT * NTN;
    const long rowA0 = (long)mT * 256;
    const long colB0 = (long)nT * 128;

    const int tid  = threadIdx.x;
    const int lane = tid & 63;
    const int wave = tid >> 6;
    const int quad = lane >> 4;
    const int l16  = lane & 15;
    const int wm   = (wave >> 1) * 64;   // 4 M-waves
    const int wn   = (wave & 1) * 64;    // 2 N-waves

    // staging: thread covers A rows rS, rS+128 and B row rS, 16B chunk cS.
    const int rS   = tid >> 2;           // 0..127
    const int cS   = tid & 3;
    const int colS = ((cS ^ ((rS >> 1) & 3)) * 8);
    const bf16* gA = A + (rowA0 + rS) * D + colS;
    const bf16* gB = W + (colB0 + rS) * D + colS;
    const int dstOff = wave * 512;       // elems; wave-uniform LDS base part

    const v4f vzero = {0.f, 0.f, 0.f, 0.f};
    v4f acc[4][4];
    #pragma unroll
    for (int i = 0; i < 4; i++)
        #pragma unroll
        for (int j = 0; j < 4; j++) acc[i][j] = vzero;

    // read offsets (elems): R*32 + ((quad ^ ((R>>1)&3))*8)
    const int rsw = (quad ^ ((l16 >> 1) & 3)) * 8;
    int sa[4], sb[4];
    #pragma unroll
    for (int i = 0; i < 4; i++) {
        sa[i] = (wm + i * 16 + l16) * 32 + rsw;
        sb[i] = (wn + i * 16 + l16) * 32 + rsw;
    }

    auto stage = [&](int bi, int t) {
        const bf16* a = gA + (long)t * 32;
        const bf16* b = gB + (long)t * 32;
        __builtin_amdgcn_global_load_lds(
            (const GAS void*)(a),
            (LAS void*)(&Abuf[bi][dstOff]), 16, 0, 0);
        __builtin_amdgcn_global_load_lds(
            (const GAS void*)(a + (long)128 * D),
            (LAS void*)(&Abuf[bi][4096 + dstOff]), 16, 0, 0);
        __builtin_amdgcn_global_load_lds(
            (const GAS void*)(b),
            (LAS void*)(&Bbuf[bi][dstOff]), 16, 0, 0);
    };

    constexpr int NT = 32;   // K=1024 / BK=32
    stage(0, 0);
    stage(1, 1);
    asm volatile("s_waitcnt vmcnt(3)" ::: "memory");
    __builtin_amdgcn_s_barrier();

    for (int t = 0; t < NT; ++t) {
        const int bi = t % 3;
        const bf16* As = &Abuf[bi][0];
        const bf16* Bs = &Bbuf[bi][0];

        // this tile's fragments (8 x ds_read_b128)
        v8bf af[4], bf4[4];
        #pragma unroll
        for (int mi = 0; mi < 4; mi++)
            af[mi] = *(const v8bf*)(As + sa[mi]);
        #pragma unroll
        for (int ni = 0; ni < 4; ni++)
            bf4[ni] = *(const v8bf*)(Bs + sb[ni]);

        // stage tile t+2 (3 x global_load_lds)
        if (t + 2 < NT) stage((t + 2) % 3, t + 2);

        // make buf[t+1] ready before crossing into it
        if (t + 1 < NT) {
            if (t + 2 < NT) asm volatile("s_waitcnt vmcnt(3)" ::: "memory");
            else            asm volatile("s_waitcnt vmcnt(0)" ::: "memory");
        }

        __builtin_amdgcn_s_barrier();
        asm volatile("s_waitcnt lgkmcnt(0)" ::: "memory");
        __builtin_amdgcn_sched_barrier(0);
        __builtin_amdgcn_s_setprio(1);
        #pragma unroll
        for (int mi = 0; mi < 4; mi++)
            #pragma unroll
            for (int ni = 0; ni < 4; ni++)
                acc[mi][ni] = __builtin_amdgcn_mfma_f32_16x16x32_bf16(
                    af[mi], bf4[ni], acc[mi][ni], 0, 0, 0);
        __builtin_amdgcn_s_setprio(0);
        __builtin_amdgcn_s_barrier();
    }

    const float qscale = 0.125f * 1.44269504f;

    if (MODE == 0) {
        const int z = (int)(colB0 >> 10);
        #pragma unroll
        for (int mi = 0; mi < 4; mi++) {
            #pragma unroll
            for (int ni = 0; ni < 4; ni++) {
                const long col = colB0 + wn + ni * 16 + l16;
                const long c   = col & 1023;
                const long row0 = rowA0 + wm + mi * 16 + quad * 4;
                if (z == 2) {
                    const long h_ = c >> 6, dd = c & 63;
                    const long b_ = row0 >> 11, s0 = row0 & 2047;
                    v4bf pk;
                    #pragma unroll
                    for (int r = 0; r < 4; r++) pk[r] = (bf16)acc[mi][ni][r];
                    *(v4bf*)(Ov + ((b_ * 16 + h_) * 64 + dd) * 2048 + s0) = pk;
                } else {
                    bf16* Ob = (z == 0) ? Oq : Ok;
                    #pragma unroll
                    for (int r = 0; r < 4; r++) {
                        float v = acc[mi][ni][r];
                        if (z == 0) v *= qscale;
                        Ob[(row0 + r) * D + c] = (bf16)v;
                    }
                }
            }
        }
    } else {
        #pragma unroll
        for (int mi = 0; mi < 4; mi++) {
            #pragma unroll
            for (int ni = 0; ni < 4; ni++) {
                const long col = colB0 + wn + ni * 16 + l16;
                const float bv = bias[col];
                #pragma unroll
                for (int r = 0; r < 4; r++) {
                    const long row = rowA0 + wm + mi * 16 + quad * 4 + r;
                    Of[row * D + col] = acc[mi][ni][r] + bv + X[row * D + col];
                }
            }
        }
    }
}

// ----------------------------------------------------------- attention ----
// 256 blocks (4 q-tiles x 64 (h,b) groups, XCD-grouped), 512 threads =
// 8 waves x 64 q-rows (q-tile 512). Per wave: TWO 32-row C-tiles share
// every K/V LDS read. l accumulated on the MFMA pipe via a ones-B MFMA.
// 4-slot K/V ring = 64 KiB -> TWO blocks/CU (4 waves/SIMD; r8/r9 ran
// 1 block/CU at 96 KiB and plateaued: MFMA 45% + VALU 38%, chained
// within-wave, no independent wave to overlap). Per pair p:
// {stage pair p+1 (4 DMA) ; compute tiles 2p,2p+1 ; vmcnt(0) ; barrier}
// -- the drain is covered by the co-resident block (m97/m114 regime).
__global__ __launch_bounds__(512, 2) void attn_kernel(
    const bf16* __restrict__ Q, const bf16* __restrict__ Kg,
    const bf16* __restrict__ VtG, bf16* __restrict__ O)
{
    const int id  = blockIdx.x;
    const int xcd = id & 7, j = id >> 3;   // j 0..31
    const int qt  = j & 3;
    const int g   = xcd + 8 * (j >> 2);    // 0..63
    const int h   = g & 15, b = g >> 4;

    const int tid  = threadIdx.x;
    const int lane = tid & 63;
    const int wave = tid >> 6;
    const int l31  = lane & 31;
    const int hi   = lane >> 5;

    __shared__ bf16 Kt[4][64 * 64];   // 32 KiB, swizzled
    __shared__ bf16 Vt[4][64 * 64];   // 32 KiB, swizzled

    // Q B-fragments: 2 q-halves x 4 d-frags, resident whole kernel.
    v8bf qB[2][4];
    #pragma unroll
    for (int qh = 0; qh < 2; qh++) {
        const long qrow = (long)(b * 2048 + qt * 512 + wave * 64 + qh * 32 + l31);
        #pragma unroll
        for (int f = 0; f < 4; f++)
            qB[qh][f] = *(const v8bf*)(Q + qrow * D + h * 64 + f * 16 + hi * 8);
    }

    const v16f z16 = {0.f,0.f,0.f,0.f,0.f,0.f,0.f,0.f,
                      0.f,0.f,0.f,0.f,0.f,0.f,0.f,0.f};
    v16f o_acc[2][2], o_l[2];
    #pragma unroll
    for (int qh = 0; qh < 2; qh++) {
        o_acc[qh][0] = z16; o_acc[qh][1] = z16; o_l[qh] = z16;
    }

    const bf16 one = (bf16)1.0f;
    v8bf ones;
    #pragma unroll
    for (int i = 0; i < 8; i++) ones[i] = one;

    // staging: row iR (0..63), 16B chunk c8; source column pre-swizzled so
    // the wave-linear DMA fill produces LDS[row][chunk c^(row&7)] layout.
    const int iR  = tid >> 3;
    const int c8  = tid & 7;
    const int csw = ((c8 ^ (iR & 7)) * 8);
    const bf16* kSrc = Kg  + (long)b * 2048 * D + h * 64 + csw + (long)iR * D;
    const bf16* vSrc = VtG + (long)(b * 16 + h) * 64 * 2048 + csw + (long)iR * 2048;
    const int ldsOff = wave * 512;   // elems; wave-uniform base, lane*16B fill

    auto stage = [&](int slot, int t) {
        __builtin_amdgcn_global_load_lds(
            (const GAS void*)(kSrc + (long)t * 64 * D),
            (LAS void*)(&Kt[slot][ldsOff]), 16, 0, 0);
        __builtin_amdgcn_global_load_lds(
            (const GAS void*)(vSrc + t * 64),
            (LAS void*)(&Vt[slot][ldsOff]), 16, 0, 0);
    };

    auto qk = [&](const bf16* kb, int ko, v16f& s0, v16f& s1) {
        const int krow = ko * 32 + l31;
        const int ksw  = krow & 7;
        v8bf kA[4];
        #pragma unroll
        for (int f = 0; f < 4; f++)
            kA[f] = *(const v8bf*)(kb + krow * 64 + (((2 * f + hi) ^ ksw) * 8));
        __builtin_amdgcn_s_setprio(1);
        s0 = __builtin_amdgcn_mfma_f32_32x32x16_bf16(kA[0], qB[0][0], z16, 0, 0, 0);
        s1 = __builtin_amdgcn_mfma_f32_32x32x16_bf16(kA[0], qB[1][0], z16, 0, 0, 0);
        #pragma unroll
        for (int f = 1; f < 4; f++) {
            s0 = __builtin_amdgcn_mfma_f32_32x32x16_bf16(kA[f], qB[0][f], s0, 0, 0, 0);
            s1 = __builtin_amdgcn_mfma_f32_32x32x16_bf16(kA[f], qB[1][f], s1, 0, 0, 0);
        }
        __builtin_amdgcn_s_setprio(0);
    };

    auto finish = [&](const bf16* vb, int ko, const v16f& s0, const v16f& s1) {
        float p0[16], p1[16];
        #pragma unroll
        for (int r = 0; r < 16; r++) {
            p0[r] = __builtin_amdgcn_exp2f(s0[r]);
            p1[r] = __builtin_amdgcn_exp2f(s1[r]);
        }
        #pragma unroll
        for (int u = 0; u < 2; u++) {
            const int s = ko * 2 + u;
            u32 a0, a1, b0, b1, c0, c1, d0, d1;
            asm("v_cvt_pk_bf16_f32 %0, %1, %2" : "=v"(a0) : "v"(p0[u*8+0]), "v"(p0[u*8+1]));
            asm("v_cvt_pk_bf16_f32 %0, %1, %2" : "=v"(a1) : "v"(p0[u*8+2]), "v"(p0[u*8+3]));
            asm("v_cvt_pk_bf16_f32 %0, %1, %2" : "=v"(b0) : "v"(p0[u*8+4]), "v"(p0[u*8+5]));
            asm("v_cvt_pk_bf16_f32 %0, %1, %2" : "=v"(b1) : "v"(p0[u*8+6]), "v"(p0[u*8+7]));
            asm("v_permlane32_swap_b32 %0, %1" : "+v"(a0), "+v"(b0));
            asm("v_permlane32_swap_b32 %0, %1" : "+v"(a1), "+v"(b1));
            asm("v_cvt_pk_bf16_f32 %0, %1, %2" : "=v"(c0) : "v"(p1[u*8+0]), "v"(p1[u*8+1]));
            asm("v_cvt_pk_bf16_f32 %0, %1, %2" : "=v"(c1) : "v"(p1[u*8+2]), "v"(p1[u*8+3]));
            asm("v_cvt_pk_bf16_f32 %0, %1, %2" : "=v"(d0) : "v"(p1[u*8+4]), "v"(p1[u*8+5]));
            asm("v_cvt_pk_bf16_f32 %0, %1, %2" : "=v"(d1) : "v"(p1[u*8+6]), "v"(p1[u*8+7]));
            asm("v_permlane32_swap_b32 %0, %1" : "+v"(c0), "+v"(d0));
            asm("v_permlane32_swap_b32 %0, %1" : "+v"(c1), "+v"(d1));
            v4u w0; w0[0] = a0; w0[1] = a1; w0[2] = b0; w0[3] = b1;
            v4u w1; w1[0] = c0; w1[1] = c1; w1[2] = d0; w1[3] = d1;
            const v8bf pa0 = __builtin_bit_cast(v8bf, w0);
            const v8bf pa1 = __builtin_bit_cast(v8bf, w1);
            const int vsw = (l31 & 7);
            v8bf vb0 = *(const v8bf*)(vb + (l31)      * 64 + (((2 * s + hi) ^ vsw) * 8));
            v8bf vb1 = *(const v8bf*)(vb + (32 + l31) * 64 + (((2 * s + hi) ^ vsw) * 8));
            __builtin_amdgcn_s_setprio(1);
            o_acc[0][0] = __builtin_amdgcn_mfma_f32_32x32x16_bf16(pa0, vb0, o_acc[0][0], 0, 0, 0);
            o_acc[0][1] = __builtin_amdgcn_mfma_f32_32x32x16_bf16(pa0, vb1, o_acc[0][1], 0, 0, 0);
            o_acc[1][0] = __builtin_amdgcn_mfma_f32_32x32x16_bf16(pa1, vb0, o_acc[1][0], 0, 0, 0);
            o_acc[1][1] = __builtin_amdgcn_mfma_f32_32x32x16_bf16(pa1, vb1, o_acc[1][1], 0, 0, 0);
            o_l[0] = __builtin_amdgcn_mfma_f32_32x32x16_bf16(pa0, ones, o_l[0], 0, 0, 0);
            o_l[1] = __builtin_amdgcn_mfma_f32_32x32x16_bf16(pa1, ones, o_l[1], 0, 0, 0);
            __builtin_amdgcn_s_setprio(0);
        }
    };

    // prologue: pair 0 into slots {0,1}
    stage(0, 0); stage(1, 1);
    asm volatile("s_waitcnt vmcnt(0)" ::: "memory");
    __builtin_amdgcn_s_barrier();

    for (int p = 0; p < 16; ++p) {
        const int sA = (p & 1) * 2;      // pair p in {0,1} or {2,3}
        // stage pair p+1 into the other slot pair (freed by last barrier)
        if (p + 1 < 16) {
            const int sS = sA ^ 2;
            stage(sS, 2 * p + 2);
            stage(sS + 1, 2 * p + 3);
        }
        const bf16* kbA = &Kt[sA][0];
        const bf16* vbA = &Vt[sA][0];
        const bf16* kbB = &Kt[sA + 1][0];
        const bf16* vbB = &Vt[sA + 1][0];
        #pragma unroll
        for (int ko = 0; ko < 2; ko++) {
            v16f sa0, sa1, sb0, sb1;
            qk(kbA, ko, sa0, sa1);
            qk(kbB, ko, sb0, sb1);      // independent MFMAs cover A's latency
            finish(vbA, ko, sa0, sa1);
            finish(vbB, ko, sb0, sb1);
        }
        if (p + 1 < 16) {
            asm volatile("s_waitcnt vmcnt(0)" ::: "memory");
            __builtin_amdgcn_s_barrier();
        }
    }

    // epilogue: o_l[qh][r] = l for C-row qp(r) (all cols equal) -- no shuffles
    const long obase = (long)(b * 2048 + qt * 512 + wave * 64);
    #pragma unroll
    for (int qh = 0; qh < 2; qh++) {
        #pragma unroll
        for (int r = 0; r < 16; r++) {
            const int qp = (r & 3) + 8 * (r >> 2) + 4 * hi;
            const float inv = 1.f / o_l[qh][r];
            const long row = obase + qh * 32 + qp;
            O[row * D + h * 64 + l31]      = (bf16)(o_acc[qh][0][r] * inv);
            O[row * D + h * 64 + 32 + l31] = (bf16)(o_acc[qh][1][r] * inv);
        }
    }
}

// ------------------------------------------------------------------ LN ----
__global__ __launch_bounds__(256) void ln_kernel(
    const float* __restrict__ g, const float* __restrict__ beta,
    float* __restrict__ out)
{
    const int row = blockIdx.x;
    const int t = threadIdx.x;
    const int lane = t & 63, wave = t >> 6;
    const long base = (long)row * D + t * 4;

    float4 yv = *(const float4*)(out + base);
    float y0 = yv.x, y1 = yv.y, y2 = yv.z, y3 = yv.w;
    float s1 = y0 + y1 + y2 + y3;
    float s2 = y0*y0 + y1*y1 + y2*y2 + y3*y3;
    #pragma unroll
    for (int off = 1; off < 64; off <<= 1) {
        s1 += __shfl_xor(s1, off);
        s2 += __shfl_xor(s2, off);
    }
    __shared__ float r1[4], r2[4];
    if (lane == 0) { r1[wave] = s1; r2[wave] = s2; }
    __syncthreads();
    float S1 = r1[0] + r1[1] + r1[2] + r1[3];
    float S2 = r2[0] + r2[1] + r2[2] + r2[3];
    float mu  = S1 * (1.f / 1024.f);
    float var = S2 * (1.f / 1024.f) - mu * mu;
    float rsd = rsqrtf(var + 1e-5f);

    float4 gv = *(const float4*)(g + t * 4);
    float4 bv = *(const float4*)(beta + t * 4);
    float4 o;
    o.x = (y0 - mu) * rsd * gv.x + bv.x;
    o.y = (y1 - mu) * rsd * gv.y + bv.y;
    o.z = (y2 - mu) * rsd * gv.z + bv.z;
    o.w = (y3 - mu) * rsd * gv.w + bv.w;
    *(float4*)(out + base) = o;
}

// ---------------------------------------------------------------- launch --
extern "C" void kernel_launch(void* const* d_in, const int* in_sizes, int n_in,
                              void* d_out, int out_size, void* d_ws, size_t ws_size,
                              hipStream_t stream)
{
    const float* x   = (const float*)d_in[0];
    const float* wq  = (const float*)d_in[1];
    const float* wk  = (const float*)d_in[2];
    const float* wv  = (const float*)d_in[3];
    const float* wo  = (const float*)d_in[4];
    const float* bo  = (const float*)d_in[5];
    const float* lng = (const float*)d_in[6];
    const float* lnb = (const float*)d_in[7];
    float* out = (float*)d_out;

    char* ws = (char*)d_ws;
    bf16* xb  = (bf16*)(ws);                            // 16 MiB
    bf16* wqb = (bf16*)(ws + (size_t)16 * 1024 * 1024); // 4 x 2 MiB (contig QKV,O)
    bf16* wkb = wqb + 1024 * 1024;
    bf16* wvb = wkb + 1024 * 1024;
    bf16* wob = wvb + 1024 * 1024;
    bf16* Qb  = (bf16*)(ws + (size_t)24 * 1024 * 1024); // 4 x 16 MiB
    bf16* Kb  = Qb + (size_t)ROWS * D;
    bf16* VtG = Kb + (size_t)ROWS * D;                  // V transposed [b][h][d][s]
    bf16* Ab  = VtG + (size_t)ROWS * D;                 // total 88 MiB

    cast_all<<<12288, 256, 0, stream>>>(x, wq, wk, wv, wo,
                                        xb, wqb, wkb, wvb, wob);

    // QKV: one dispatch, W = [3072][1024] (wq|wk|wv contiguous).
    gemm8<0, 24><<<768, 512, 0, stream>>>(xb, wqb, Qb, Kb, VtG,
                                          nullptr, nullptr, nullptr);

    attn_kernel<<<dim3(256, 1, 1), 512, 0, stream>>>(Qb, Kb, VtG, Ab);

    // Output proj: 256 blocks, all co-resident at 2 blocks/CU.
    gemm8<1, 8><<<256, 512, 0, stream>>>(Ab, wob, nullptr, nullptr, nullptr,
                                         out, bo, x);

    ln_kernel<<<8192, 256, 0, stream>>>(lng, lnb, out);
}